// Round 1
// baseline (76.803 us; speedup 1.0000x reference)
//
#include <hip/hip_runtime.h>

// Round 5: two-dispatch split of the affine-scan RK4 integrator.
// s = [y0, y1, v0, v1];  s_{t+1} = A s_t + B u_t  (A 4x4, B 4x2 constant).
//
// vs round 4: the single-kernel decoupled lookback (agent-scope acquire spin
// + __threadfence + release store) is replaced by two dispatches relying on
// kernel-boundary coherence. On gfx950 the per-XCD L2s are non-coherent, so
// every agent-scope acquire/release implies L2 cache-maintenance ops; right
// after the harness's 268 MB workspace poison those ops hit a dirty L2.
// Kernel A: tables + per-chunk transform + block scan -> plain stores of
//   agg[b], exclusive prefixes Ebuf[j], and the power tables.
// Kernel B: reads everything back (no fences needed), resolves the block
//   start state with one 64-lane weighted reduction, places with one mv4,
//   emits 16 steps from registers.

#define LSTEP  16
#define TPB    256
#define MAXNB  64    // fused path supports <= 64 blocks (one lookback wave)

// ---------------- f64 exact one-step RK4 map ----------------
__device__ inline void accel_d(const double* M, const double* Cm, const double* Km,
                               const double* u, const double* z, const double* v, double* a) {
  a[0] = (u[0] - Cm[0] * v[0] - Cm[1] * v[1] - Km[0] * z[0] - Km[1] * z[1]) / M[0];
  a[1] = (u[1] - Cm[2] * v[0] - Cm[3] * v[1] - Km[2] * z[0] - Km[3] * z[1]) / M[1];
}

__device__ inline void rk4_step_d(const double* M, const double* Cm, const double* Km,
                                  double dt, double* y, double* v, const double* u) {
  double k1[2], k2[2], k3[2], k4[2];
  double y2[2], v2[2], y3[2], v3[2], y4[2], v4[2];
  double h = dt * 0.5;
  accel_d(M, Cm, Km, u, y, v, k1);
  y2[0] = y[0] + v[0] * h;  y2[1] = y[1] + v[1] * h;
  v2[0] = v[0] + k1[0] * h; v2[1] = v[1] + k1[1] * h;
  accel_d(M, Cm, Km, u, y2, v2, k2);
  y3[0] = y[0] + v2[0] * h;  y3[1] = y[1] + v2[1] * h;
  v3[0] = v[0] + k2[0] * h;  v3[1] = v[1] + k2[1] * h;
  accel_d(M, Cm, Km, u, y3, v3, k3);
  y4[0] = y[0] + v3[0] * dt; y4[1] = y[1] + v3[1] * dt;
  v4[0] = v[0] + k3[0] * dt; v4[1] = v[1] + k3[1] * dt;
  accel_d(M, Cm, Km, u, y4, v4, k4);
  double s = dt / 6.0;
  double yn0 = y[0] + s * (v[0] + 2.0 * v2[0] + 2.0 * v3[0] + v4[0]);
  double yn1 = y[1] + s * (v[1] + 2.0 * v2[1] + 2.0 * v3[1] + v4[1]);
  double vn0 = v[0] + s * (k1[0] + 2.0 * k2[0] + 2.0 * k3[0] + k4[0]);
  double vn1 = v[1] + s * (k1[1] + 2.0 * k2[1] + 2.0 * k3[1] + k4[1]);
  y[0] = yn0; y[1] = yn1; v[0] = vn0; v[1] = vn1;
}

// threads 0..5 build columns of A (basis states) / B (basis inputs) in f64.
__device__ inline void build_cols(const float* Mp, const float* Cp, const float* Kp,
                                  const float* dtp, float* Af, float* Bf, double* Ad) {
  int tid = threadIdx.x;
  if (tid < 6) {
    double M[2]  = {(double)Mp[0], (double)Mp[1]};
    double Cm[4] = {(double)Cp[0] + (double)Cp[1], -(double)Cp[1],
                    -(double)Cp[1], (double)Cp[2] + (double)Cp[1]};
    double Km[4] = {(double)Kp[0] + (double)Kp[1], -(double)Kp[1],
                    -(double)Kp[1], (double)Kp[2] + (double)Kp[1]};
    double dt = (double)dtp[0];
    double y[2] = {0, 0}, v[2] = {0, 0}, u[2] = {0, 0};
    if      (tid == 0) y[0] = 1.0;
    else if (tid == 1) y[1] = 1.0;
    else if (tid == 2) v[0] = 1.0;
    else if (tid == 3) v[1] = 1.0;
    else if (tid == 4) u[0] = 1.0;
    else               u[1] = 1.0;
    rk4_step_d(M, Cm, Km, dt, y, v, u);
    if (tid < 4) {
      Af[0 * 4 + tid] = (float)y[0]; Af[1 * 4 + tid] = (float)y[1];
      Af[2 * 4 + tid] = (float)v[0]; Af[3 * 4 + tid] = (float)v[1];
      Ad[0 * 4 + tid] = y[0]; Ad[1 * 4 + tid] = y[1];
      Ad[2 * 4 + tid] = v[0]; Ad[3 * 4 + tid] = v[1];
    } else {
      int j = tid - 4;
      Bf[0 * 2 + j] = (float)y[0]; Bf[1 * 2 + j] = (float)y[1];
      Bf[2 * 2 + j] = (float)v[0]; Bf[3 * 2 + j] = (float)v[1];
    }
  }
}

// ---------------- f32 helpers ----------------
__device__ inline float4 mv4(const float* A, float4 x) {
  float4 r;
  r.x = A[0]  * x.x + A[1]  * x.y + A[2]  * x.z + A[3]  * x.w;
  r.y = A[4]  * x.x + A[5]  * x.y + A[6]  * x.z + A[7]  * x.w;
  r.z = A[8]  * x.x + A[9]  * x.y + A[10] * x.z + A[11] * x.w;
  r.w = A[12] * x.x + A[13] * x.y + A[14] * x.z + A[15] * x.w;
  return r;
}
__device__ inline float4 f4add(float4 a, float4 b) {
  return make_float4(a.x + b.x, a.y + b.y, a.z + b.z, a.w + b.w);
}
__device__ inline float4 stepf(const float* a, const float* b, float4 s, float2 ut) {
  float4 r;
  r.x = a[0]  * s.x + a[1]  * s.y + a[2]  * s.z + a[3]  * s.w + b[0] * ut.x + b[1] * ut.y;
  r.y = a[4]  * s.x + a[5]  * s.y + a[6]  * s.z + a[7]  * s.w + b[2] * ut.x + b[3] * ut.y;
  r.z = a[8]  * s.x + a[9]  * s.y + a[10] * s.z + a[11] * s.w + b[4] * ut.x + b[5] * ut.y;
  r.w = a[12] * s.x + a[13] * s.y + a[14] * s.z + a[15] * s.w + b[6] * ut.x + b[7] * ut.y;
  return r;
}
// Z = X * Y (4x4 f32, row-major)
__device__ inline void mm4(const float* X, const float* Y, float* Z) {
#pragma unroll
  for (int i = 0; i < 4; ++i)
#pragma unroll
    for (int j = 0; j < 4; ++j)
      Z[i * 4 + j] = X[i * 4 + 0] * Y[0 * 4 + j] + X[i * 4 + 1] * Y[1 * 4 + j]
                   + X[i * 4 + 2] * Y[2 * 4 + j] + X[i * 4 + 3] * Y[3 * 4 + j];
}

// 4x4 f64 matmul across lanes 0..15 of wave 0; lane holds element (i,j).
__device__ inline double matmul16(double a, double b, int i, int j) {
  double acc = 0.0;
#pragma unroll
  for (int k = 0; k < 4; ++k)
    acc += __shfl(a, i * 4 + k) * __shfl(b, k * 4 + j);
  return acc;
}

// ---------------- kernel A: tables + per-chunk transform + block scan ----------------
__global__ __launch_bounds__(TPB) void kScan(
    const float* __restrict__ u, const float* M, const float* C, const float* K,
    const float* dtp, int T,
    float4* __restrict__ agg, float4* __restrict__ Ebuf,
    float* __restrict__ TabT, float* __restrict__ TabW,
    float* __restrict__ TabA, float* __restrict__ TabB) {
  __shared__ float  Af[16], Bf[8];
  __shared__ double Ad[16];
  __shared__ __align__(16) float Tt[256][16];  // Tt[k] = A^(16k)
  __shared__ __align__(16) float Wt[64][16];   // Wt[k] = A^(4096k)
  __shared__ float4 S[TPB];

  int tid = threadIdx.x;
  int b   = blockIdx.x;

  // issue u loads early (independent of table building)
  int j  = b * TPB + tid;
  int t0 = j * LSTEP;
  bool full = (t0 + LSTEP <= T);
  float4 uu[LSTEP / 2];
  if (full) {
    const float4* u4 = (const float4*)(u + 2 * t0);
#pragma unroll
    for (int i = 0; i < LSTEP / 2; ++i) uu[i] = u4[i];
  }

  build_cols(M, C, K, dtp, Af, Bf, Ad);
  if (tid == 0) {
#pragma unroll
    for (int e = 0; e < 16; ++e) {
      float v = ((e >> 2) == (e & 3)) ? 1.f : 0.f;
      Tt[0][e] = v; Wt[0][e] = v;
    }
  }
  __syncthreads();

  // f64 squaring chain: seed power-of-two entries of both tables.
  // lvl 17 gives A^(4096*32) so Wt is valid up to 64 blocks.
  if (tid < 16) {
    int i = tid >> 2, jj = tid & 3;
    double m = Ad[tid];
#pragma unroll
    for (int lvl = 1; lvl <= 17; ++lvl) {
      m = matmul16(m, m, i, jj);                       // m = A^(2^lvl)
      if (lvl >= 4 && lvl <= 11) Tt[1 << (lvl - 4)][tid] = (float)m;   // A^(16*2^(lvl-4))
      if (lvl >= 12)             Wt[1 << (lvl - 12)][tid] = (float)m;  // A^(4096*2^(lvl-12))
    }
  }
  __syncthreads();

  // log-doubling fill of non-power entries
#pragma unroll
  for (int d = 1; d < 8; ++d) {
    int off = 1 << d;
    if (tid > off && tid < 2 * off)          // Tt[k] = Tt[k-off] * Tt[off]
      mm4(&Tt[tid - off][0], &Tt[off][0], &Tt[tid][0]);
    if (d <= 5 && tid >= 128) {              // Wt fill via threads 128+k
      int k = tid - 128;
      if (k > off && k < 2 * off && k < 64)
        mm4(&Wt[k - off][0], &Wt[off][0], &Wt[k][0]);
    }
    __syncthreads();
  }

  float a[16], bb[8];
#pragma unroll
  for (int e = 0; e < 16; ++e) a[e] = Af[e];
#pragma unroll
  for (int e = 0; e < 8; ++e) bb[e] = Bf[e];

  // phase 1: chunk transform from zero start (u in registers)
  float4 c = make_float4(0.f, 0.f, 0.f, 0.f);
  if (full) {
#pragma unroll
    for (int i = 0; i < LSTEP / 2; ++i) {
      c = stepf(a, bb, c, make_float2(uu[i].x, uu[i].y));
      c = stepf(a, bb, c, make_float2(uu[i].z, uu[i].w));
    }
  } else {
    const float2* u2 = (const float2*)u;
    for (int i = 0; i < LSTEP; ++i) {
      int t = t0 + i;
      if (t >= T) break;
      c = stepf(a, bb, c, u2[t]);
    }
  }

  // phase 2: block weighted inclusive scan (weights Tt[2^k])
  S[tid] = c;
  __syncthreads();
#pragma unroll
  for (int k = 0; k < 8; ++k) {
    int off = 1 << k;
    float4 add = make_float4(0.f, 0.f, 0.f, 0.f);
    bool act = (tid >= off);
    if (act) add = mv4(&Tt[off][0], S[tid - off]);
    __syncthreads();
    if (act) S[tid] = f4add(S[tid], add);
    __syncthreads();
  }

  // outputs: plain stores; kernel boundary provides coherence.
  Ebuf[j] = (tid == 0) ? make_float4(0.f, 0.f, 0.f, 0.f) : S[tid - 1];
  if (tid == TPB - 1) agg[b] = S[tid];
  if (b == 0) {
    float4*       dstT = (float4*)(TabT + tid * 16);
    const float4* srcT = (const float4*)&Tt[tid][0];
#pragma unroll
    for (int e = 0; e < 4; ++e) dstT[e] = srcT[e];
    if (tid < 64) {
      float4*       dstW = (float4*)(TabW + tid * 16);
      const float4* srcW = (const float4*)&Wt[tid][0];
#pragma unroll
      for (int e = 0; e < 4; ++e) dstW[e] = srcW[e];
    }
    if (tid < 16) TabA[tid] = Af[tid];
    if (tid < 8)  TabB[tid] = Bf[tid];
  }
}

// ---------------- kernel B: resolve block start, place, emit ----------------
__global__ __launch_bounds__(TPB) void kEmit(
    const float* __restrict__ u, const float* __restrict__ x0, int T,
    const float4* __restrict__ agg, const float4* __restrict__ Ebuf,
    const float* __restrict__ TabT, const float* __restrict__ TabW,
    const float* __restrict__ TabA, const float* __restrict__ TabB,
    float2* __restrict__ out) {
  __shared__ float  Afs[16], Bfs[8];
  __shared__ float4 sBsh;

  int tid = threadIdx.x;
  int b   = blockIdx.x;
  int j   = b * TPB + tid;
  int t0  = j * LSTEP;
  bool full = (t0 + LSTEP <= T);

  float4 uu[LSTEP / 2];
  if (full) {
    const float4* u4 = (const float4*)(u + 2 * t0);
#pragma unroll
    for (int i = 0; i < LSTEP / 2; ++i) uu[i] = u4[i];
  }

  // own placement row Tt[tid] = A^(16*tid) and exclusive prefix
  const float4* tr = (const float4*)(TabT + tid * 16);
  float4 T0 = tr[0], T1 = tr[1], T2 = tr[2], T3 = tr[3];
  float4 E  = Ebuf[j];

  if (tid < 16)       Afs[tid] = TabA[tid];
  else if (tid < 24)  Bfs[tid - 16] = TabB[tid - 16];

  // lookback: one wave combines all predecessor aggregates + x0
  float4 s0v = make_float4(x0[0], x0[2], x0[1], x0[3]);
  if (tid < 64) {
    float4 acc = make_float4(0.f, 0.f, 0.f, 0.f);
    if (tid < b)        acc = mv4(TabW + (size_t)(b - 1 - tid) * 16, agg[tid]);
    else if (tid == b)  acc = mv4(TabW + (size_t)b * 16, s0v);
#pragma unroll
    for (int o2 = 32; o2 >= 1; o2 >>= 1) {
      acc.x += __shfl_xor(acc.x, o2);
      acc.y += __shfl_xor(acc.y, o2);
      acc.z += __shfl_xor(acc.z, o2);
      acc.w += __shfl_xor(acc.w, o2);
    }
    if (tid == 0) sBsh = acc;
  }
  __syncthreads();
  float4 sB = sBsh;

  // place chunk start state
  float4 st;
  st.x = T0.x * sB.x + T0.y * sB.y + T0.z * sB.z + T0.w * sB.w + E.x;
  st.y = T1.x * sB.x + T1.y * sB.y + T1.z * sB.z + T1.w * sB.w + E.y;
  st.z = T2.x * sB.x + T2.y * sB.y + T2.z * sB.z + T2.w * sB.w + E.z;
  st.w = T3.x * sB.x + T3.y * sB.y + T3.z * sB.z + T3.w * sB.w + E.w;

  float a[16], bb[8];
#pragma unroll
  for (int e = 0; e < 16; ++e) a[e] = Afs[e];
#pragma unroll
  for (int e = 0; e < 8; ++e) bb[e] = Bfs[e];

  // emit from registers
  if (full) {
    float4* o4 = (float4*)(out + t0);
#pragma unroll
    for (int i = 0; i < LSTEP / 2; ++i) {
      st = stepf(a, bb, st, make_float2(uu[i].x, uu[i].y));
      float2 ya = make_float2(st.x, st.y);
      st = stepf(a, bb, st, make_float2(uu[i].z, uu[i].w));
      o4[i] = make_float4(ya.x, ya.y, st.x, st.y);
    }
  } else {
    const float2* u2 = (const float2*)u;
    for (int i = 0; i < LSTEP; ++i) {
      int t = t0 + i;
      if (t >= T) break;
      st = stepf(a, bb, st, u2[t]);
      out[t] = make_float2(st.x, st.y);
    }
  }
}

// ---------------- fallback: exact serial f64 ----------------
__global__ void kSerialAll(const float* u, const float* Mp, const float* Cp, const float* Kp,
                           const float* dtp, const float* x0, int T, float2* out) {
  if (threadIdx.x != 0 || blockIdx.x != 0) return;
  double M[2]  = {(double)Mp[0], (double)Mp[1]};
  double Cm[4] = {(double)Cp[0] + (double)Cp[1], -(double)Cp[1],
                  -(double)Cp[1], (double)Cp[2] + (double)Cp[1]};
  double Km[4] = {(double)Kp[0] + (double)Kp[1], -(double)Kp[1],
                  -(double)Kp[1], (double)Kp[2] + (double)Kp[1]};
  double dt = (double)dtp[0];
  double y[2] = {(double)x0[0], (double)x0[2]};
  double v[2] = {(double)x0[1], (double)x0[3]};
  for (int t = 0; t < T; ++t) {
    double uu[2] = {(double)u[2 * t], (double)u[2 * t + 1]};
    rk4_step_d(M, Cm, Km, dt, y, v, uu);
    out[t] = make_float2((float)y[0], (float)y[1]);
  }
}

extern "C" void kernel_launch(void* const* d_in, const int* in_sizes, int n_in,
                              void* d_out, int out_size, void* d_ws, size_t ws_size,
                              hipStream_t stream) {
  (void)n_in; (void)out_size;
  const float* u   = (const float*)d_in[0];
  const float* M   = (const float*)d_in[1];
  const float* C   = (const float*)d_in[2];
  const float* K   = (const float*)d_in[3];
  const float* x0  = (const float*)d_in[4];
  const float* dt  = (const float*)d_in[5];
  int T = in_sizes[0] / 2;
  float2* out = (float2*)d_out;

  int nch = (T + LSTEP - 1) / LSTEP;
  int nb  = (nch + TPB - 1) / TPB;

  // ws layout: agg[64] | Ebuf[64*256] | TabT[256*16] | TabW[64*16] | TabA[16] | TabB[8]
  size_t need = sizeof(float4) * MAXNB
              + sizeof(float4) * (size_t)MAXNB * TPB
              + sizeof(float) * (256 * 16 + 64 * 16 + 16 + 8);
  if (nb > MAXNB || ws_size < need) {
    kSerialAll<<<1, 64, 0, stream>>>(u, M, C, K, dt, x0, T, out);
    return;
  }
  float4* agg  = (float4*)d_ws;
  float4* Ebuf = agg + MAXNB;
  float*  TabT = (float*)(Ebuf + (size_t)MAXNB * TPB);
  float*  TabW = TabT + 256 * 16;
  float*  TabA = TabW + 64 * 16;
  float*  TabB = TabA + 16;

  kScan<<<nb, TPB, 0, stream>>>(u, M, C, K, dt, T, agg, Ebuf, TabT, TabW, TabA, TabB);
  kEmit<<<nb, TPB, 0, stream>>>(u, x0, T, agg, Ebuf, TabT, TabW, TabA, TabB, out);
}